// Round 4
// baseline (668.533 us; speedup 1.0000x reference)
//
#include <hip/hip_runtime.h>
#include <hip/hip_bf16.h>
#include <cstdint>
#include <cstddef>

#define DEPTH 4
#define DIM 512
#define DFF 2048
#define VOCAB 4096
#define NB 2
#define LSEQ 4096
#define MR (NB*LSEQ)      // 8192 rows
#define EPSL 1e-5f
#define NC 128            // scan chunks per sequence
#define TCH 32            // chunk length (NC*TCH == LSEQ)

typedef __attribute__((ext_vector_type(8))) short  s8v;
typedef __attribute__((ext_vector_type(4))) float  f4v;
typedef __attribute__((ext_vector_type(8))) __bf16 bf8v;

__device__ __forceinline__ unsigned short f2b(float f) {
  union { float f; unsigned int u; } v; v.f = f;
  unsigned int r = v.u + 0x7FFFu + ((v.u >> 16) & 1u);   // RNE
  return (unsigned short)(r >> 16);
}

// global->LDS direct load, 16B per lane (LDS dest: wave-uniform base + lane*16).
__device__ __forceinline__ void gld16(const void* g, void* l) {
  __builtin_amdgcn_global_load_lds(
      (const __attribute__((address_space(1))) unsigned int*)(uintptr_t)g,
      (__attribute__((address_space(3))) unsigned int*)(uintptr_t)l,
      16, 0, 0);
}

// ---------------- f32 -> bf16 convert (8 elems/thread) ----------------
__global__ void __launch_bounds__(256) cvt_f32_bf16(
    const float* __restrict__ in, unsigned short* __restrict__ out, int n8)
{
  int i = blockIdx.x * 256 + threadIdx.x;
  if (i >= n8) return;
  const f4v* p = (const f4v*)(in + (size_t)i * 8);
  f4v a = p[0], b = p[1];
  s8v o;
  o[0]=(short)f2b(a[0]); o[1]=(short)f2b(a[1]); o[2]=(short)f2b(a[2]); o[3]=(short)f2b(a[3]);
  o[4]=(short)f2b(b[0]); o[5]=(short)f2b(b[1]); o[6]=(short)f2b(b[2]); o[7]=(short)f2b(b[3]);
  *(s8v*)(out + (size_t)i * 8) = o;
}

// ---------------- LayerNorm (1 wave / 512-row) ----------------
// MODE 0: out = silu(LN(x)) as f32 ; MODE 1: out = LN(x) as bf16
template<int MODE>
__global__ void __launch_bounds__(256) ln_kernel(
    const float* __restrict__ x, const float* __restrict__ w, const float* __restrict__ b,
    float* __restrict__ outf, unsigned short* __restrict__ outb)
{
  int row  = blockIdx.x * 4 + (threadIdx.x >> 6);
  int lane = threadIdx.x & 63;
  const float* xp = x + (size_t)row * DIM + lane * 8;
  f4v v0 = *(const f4v*)xp;
  f4v v1 = *(const f4v*)(xp + 4);
  float s = 0.f, s2 = 0.f;
#pragma unroll
  for (int j = 0; j < 4; ++j) { s += v0[j]; s2 += v0[j]*v0[j]; s += v1[j]; s2 += v1[j]*v1[j]; }
#pragma unroll
  for (int off = 32; off; off >>= 1) { s += __shfl_xor(s, off, 64); s2 += __shfl_xor(s2, off, 64); }
  float mu = s * (1.f / DIM);
  float rs = rsqrtf(s2 * (1.f / DIM) - mu * mu + EPSL);
  int c = lane * 8;
  f4v w0 = *(const f4v*)(w + c), w1 = *(const f4v*)(w + c + 4);
  f4v b0 = *(const f4v*)(b + c), b1 = *(const f4v*)(b + c + 4);
  float ov[8];
#pragma unroll
  for (int j = 0; j < 8; ++j) {
    float xv = (j < 4) ? v0[j] : v1[j - 4];
    float wv = (j < 4) ? w0[j] : w1[j - 4];
    float bv = (j < 4) ? b0[j] : b1[j - 4];
    float o = (xv - mu) * rs * wv + bv;
    if (MODE == 0) o = o / (1.f + __expf(-o));   // silu
    ov[j] = o;
  }
  if (MODE == 0) {
    f4v o0 = {ov[0], ov[1], ov[2], ov[3]};
    f4v o1 = {ov[4], ov[5], ov[6], ov[7]};
    *(f4v*)(outf + (size_t)row * DIM + c)     = o0;
    *(f4v*)(outf + (size_t)row * DIM + c + 4) = o1;
  } else {
    s8v o;
#pragma unroll
    for (int j = 0; j < 8; ++j) o[j] = (short)f2b(ov[j]);
    *(s8v*)(outb + (size_t)row * DIM + c) = o;
  }
}

// ---------------- sconv scan ----------------
__device__ __forceinline__ void phz2p(float re, float im, float& pre, float& pim) {
  float r = sqrtf(re * re + im * im);
  float t = (r > 1e-20f) ? (tanhf(r) / r) : 1.0f;
  pre = t * re; pim = t * im;
}

// Phase A: per-chunk local scan from 0; store chunk-end state [NB][NC][DIM][2]
__global__ void __launch_bounds__(256) scan_a(
    const float* __restrict__ y, const float* __restrict__ pr, const float* __restrict__ pi,
    float* __restrict__ stA)
{
  int d = blockIdx.z * 256 + threadIdx.x;
  int b = blockIdx.y, c = blockIdx.x;
  float pre, pim; phz2p(pr[d], pi[d], pre, pim);
  const float* yp = y + ((size_t)b * LSEQ + (size_t)c * TCH) * DIM + d;
  float sre = 0.f, sim = 0.f;
#pragma unroll 8
  for (int j = 0; j < TCH; ++j) {
    float xv = yp[(size_t)j * DIM];
    float nre = fmaf(pre, sre, fmaf(-pim, sim, xv));
    float nim = fmaf(pre, sim, pim * sre);
    sre = nre; sim = nim;
  }
  size_t o = (((size_t)b * NC + c) * DIM + d) * 2;
  stA[o] = sre; stA[o + 1] = sim;
}

// Phase B: sequential carry over chunks; carry[b][c] = state entering chunk c
__global__ void __launch_bounds__(256) scan_b(
    const float* __restrict__ stA, float* __restrict__ carry,
    const float* __restrict__ pr, const float* __restrict__ pi,
    const float* __restrict__ lcr, const float* __restrict__ lci)
{
  int idx = blockIdx.x * 256 + threadIdx.x;   // 0..NB*DIM-1
  int b = idx >> 9, d = idx & (DIM - 1);
  float pre, pim; phz2p(pr[d], pi[d], pre, pim);
  float qre = pre, qim = pim;                  // p^TCH, TCH=32 -> 5 squarings
#pragma unroll
  for (int t = 0; t < 5; ++t) { float nr = qre*qre - qim*qim; float ni = 2.f*qre*qim; qre = nr; qim = ni; }
  float cre = lcr[d], cim = lci[d];
#pragma unroll 4
  for (int c = 0; c < NC; ++c) {
    size_t o = (((size_t)b * NC + c) * DIM + d) * 2;
    carry[o] = cre; carry[o + 1] = cim;
    float are = stA[o], aim = stA[o + 1];
    float nr = fmaf(qre, cre, fmaf(-qim, cim, are));
    float ni = fmaf(qre, cim, fmaf(qim, cre, aim));
    cre = nr; cim = ni;
  }
}

// Phase C: replay chunk with true carry; fused h += Re(s)*scl
__global__ void __launch_bounds__(256) scan_c(
    const float* __restrict__ y, float* __restrict__ h, const float* __restrict__ carry,
    const float* __restrict__ pr, const float* __restrict__ pi,
    const float* __restrict__ scl)
{
  int d = blockIdx.z * 256 + threadIdx.x;
  int b = blockIdx.y, c = blockIdx.x;
  float pre, pim; phz2p(pr[d], pi[d], pre, pim);
  size_t o = (((size_t)b * NC + c) * DIM + d) * 2;
  float sre = carry[o], sim = carry[o + 1];
  float sc = scl[d];
  const float* yp = y + ((size_t)b * LSEQ + (size_t)c * TCH) * DIM + d;
  float*       hp = h + ((size_t)b * LSEQ + (size_t)c * TCH) * DIM + d;
#pragma unroll 8
  for (int j = 0; j < TCH; ++j) {
    float xv = yp[(size_t)j * DIM];
    float nre = fmaf(pre, sre, fmaf(-pim, sim, xv));
    float nim = fmaf(pre, sim, pim * sre);
    sre = nre; sim = nim;
    hp[(size_t)j * DIM] += sre * sc;
  }
}

// ---------------- bf16 MFMA GEMM, A[M,K] x B[N,K]^T, 128x128 tile ----------------
// R2-proven 2-phase structure (__syncthreads sync). Split-K via blockIdx.z:
// block z handles K-slice [z*Keff, (z+1)*Keff); lda/ldb are full row strides.
// AF32=1: A is f32 in global; reg-stage with fused f32->bf16 convert.
// EPI 0: Cf = acc + bias            (f32)
// EPI 1: Cb = bf16(silu(acc+bias))  (bf16)
// EPI 3: Cf[z*MR*N + off] = acc     (raw split-K partial, no bias)
template<int EPI, int AF32>
__global__ void __launch_bounds__(256, 4) gemm_bt(
    const void* __restrict__ Ap, const unsigned short* __restrict__ Bm,
    const float* __restrict__ bias,
    float* __restrict__ Cf, unsigned short* __restrict__ Cb,
    int N, int Keff, int lda, int ldb)
{
  __shared__ unsigned short As[2][128 * 32];
  __shared__ unsigned short Bs[2][128 * 32];
  const int tid  = threadIdx.x;
  const int lane = tid & 63, wave = tid >> 6;
  const int wm = wave >> 1, wn = wave & 1;
  const int fr = lane & 15, fq = lane >> 4;
  const int bz = blockIdx.z;

  // chunked bijective XCD swizzle within each z-slice (nwg_xy % 8 == 0 for all grids)
  int bx, by;
  {
    int gx = gridDim.x;
    int nwg = gx * gridDim.y;
    int b = blockIdx.y * gx + blockIdx.x;
    int lid = (b & 7) * (nwg >> 3) + (b >> 3);
    bx = lid % gx; by = lid / gx;
  }
  const int m0 = by * 128, n0 = bx * 128;
  const int koff = bz * Keff;

  f4v acc[4][4];
#pragma unroll
  for (int i = 0; i < 4; ++i)
#pragma unroll
    for (int j = 0; j < 4; ++j) acc[i][j] = (f4v){0.f, 0.f, 0.f, 0.f};

  const int nkt = Keff >> 5;

  f4v areg[2][2];
  auto loadA = [&](int k0) {   // AF32: issue global f32 loads into regs
    const float* Ab = (const float*)Ap + (size_t)m0 * lda + koff + k0;
#pragma unroll
    for (int r = 0; r < 2; ++r) {
      int idx = r * 256 + tid;
      int row = idx >> 2, col = (idx & 3) << 3;
      const float* p = Ab + (size_t)row * lda + col;
      areg[r][0] = *(const f4v*)p;
      areg[r][1] = *(const f4v*)(p + 4);
    }
  };
  auto writeA = [&](int buf) { // AF32: cvt + ds_write (late)
#pragma unroll
    for (int r = 0; r < 2; ++r) {
      int idx = r * 256 + tid;
      s8v o;
#pragma unroll
      for (int j = 0; j < 4; ++j) {
        o[j]     = (short)f2b(areg[r][0][j]);
        o[4 + j] = (short)f2b(areg[r][1][j]);
      }
      *(s8v*)&As[buf][idx * 8] = o;
    }
  };
  auto stageA16 = [&](int buf, int k0) {
    const unsigned short* Ab = (const unsigned short*)Ap + (size_t)m0 * lda + koff + k0;
#pragma unroll
    for (int r = 0; r < 2; ++r) {
      int idx = r * 256 + tid;
      int row = idx >> 2, col = (idx & 3) << 3;
      gld16(Ab + (size_t)row * lda + col, &As[buf][idx * 8]);
    }
  };
  auto stageB = [&](int buf, int k0) {
    const unsigned short* Bb = Bm + (size_t)n0 * ldb + koff + k0;
#pragma unroll
    for (int r = 0; r < 2; ++r) {
      int idx = r * 256 + tid;
      int row = idx >> 2, col = (idx & 3) << 3;
      gld16(Bb + (size_t)row * ldb + col, &Bs[buf][idx * 8]);
    }
  };

  if constexpr (AF32) loadA(0); else stageA16(0, 0);
  stageB(0, 0);
  if constexpr (AF32) writeA(0);
  __syncthreads();

  for (int kt = 0; kt < nkt; ++kt) {
    int cur = kt & 1;
    bool pf = (kt + 1 < nkt);
    if (pf) {                               // issue next-tile loads early
      if constexpr (AF32) loadA((kt + 1) << 5);
      else stageA16(cur ^ 1, (kt + 1) << 5);
      stageB(cur ^ 1, (kt + 1) << 5);
    }
    bf8v av[4], bv[4];
#pragma unroll
    for (int i = 0; i < 4; ++i)
      av[i] = *(const bf8v*)&As[cur][(wm * 64 + i * 16 + fr) * 32 + fq * 8];
#pragma unroll
    for (int j = 0; j < 4; ++j)
      bv[j] = *(const bf8v*)&Bs[cur][(wn * 64 + j * 16 + fr) * 32 + fq * 8];
#pragma unroll
    for (int i = 0; i < 4; ++i)
#pragma unroll
      for (int j = 0; j < 4; ++j)
        acc[i][j] = __builtin_amdgcn_mfma_f32_16x16x32_bf16(av[i], bv[j], acc[i][j], 0, 0, 0);
    if (pf) { if constexpr (AF32) writeA(cur ^ 1); }  // write-late
    __syncthreads();
  }

  // epilogue: C[m0 + wm*64 + i*16 + fq*4 + r][n0 + wn*64 + j*16 + fr]
  const size_t pbase = (EPI == 3) ? (size_t)bz * MR * N : 0;
#pragma unroll
  for (int j = 0; j < 4; ++j) {
    const int col = n0 + wn * 64 + j * 16 + fr;
    const float bsv = (EPI == 3) ? 0.f : bias[col];
#pragma unroll
    for (int i = 0; i < 4; ++i) {
#pragma unroll
      for (int r = 0; r < 4; ++r) {
        const int row = m0 + wm * 64 + i * 16 + fq * 4 + r;
        const size_t off = (size_t)row * N + col;
        float v = acc[i][j][r] + bsv;
        if constexpr (EPI == 0) {
          Cf[off] = v;
        } else if constexpr (EPI == 1) {
          float sv = v / (1.f + __expf(-v));
          Cb[off] = f2b(sv);
        } else {
          Cf[pbase + off] = v;
        }
      }
    }
  }
}

// ---------------- split-K reduce: out = (RES? out:0) + sum_4(parts) + bias ----------------
template<int RES>
__global__ void __launch_bounds__(256) reduce_sk(
    const float* __restrict__ parts, const float* __restrict__ bias,
    float* __restrict__ out)
{
  size_t i = ((size_t)blockIdx.x * 256 + threadIdx.x) * 4;
  const size_t st = (size_t)MR * DIM;
  f4v v = *(const f4v*)(parts + i);
  v += *(const f4v*)(parts + st + i);
  v += *(const f4v*)(parts + 2 * st + i);
  v += *(const f4v*)(parts + 3 * st + i);
  int c = (int)(i & (DIM - 1));
  v += *(const f4v*)(bias + c);
  if (RES) v += *(const f4v*)(out + i);
  *(f4v*)(out + i) = v;
}

// ---------------- orchestration ----------------
extern "C" void kernel_launch(void* const* d_in, const int* in_sizes, int n_in,
                              void* d_out, int out_size, void* d_ws, size_t ws_size,
                              hipStream_t stream)
{
  (void)in_sizes; (void)n_in; (void)out_size; (void)ws_size;
  const float* x    = (const float*)d_in[0];
  const float* Win  = (const float*)d_in[1];
  const float* bin  = (const float*)d_in[2];
  const float* ln1w = (const float*)d_in[3];
  const float* ln1b = (const float*)d_in[4];
  const float* phzr = (const float*)d_in[5];
  const float* phzi = (const float*)d_in[6];
  const float* lcr  = (const float*)d_in[7];
  const float* lci  = (const float*)d_in[8];
  const float* scl  = (const float*)d_in[9];
  const float* ln2w = (const float*)d_in[10];
  const float* ln2b = (const float*)d_in[11];
  const float* W1   = (const float*)d_in[12];
  const float* b1   = (const float*)d_in[13];
  const float* W2   = (const float*)d_in[14];
  const float* b2   = (const float*)d_in[15];
  const float* lnlw = (const float*)d_in[16];
  const float* lnlb = (const float*)d_in[17];
  const float* Wout = (const float*)d_in[18];
  const float* bout = (const float*)d_in[19];

  char* wsp = (char*)d_ws;
  auto alloc = [&](size_t bytes) { char* p = wsp; wsp += (bytes + 255) & ~(size_t)255; return p; };
  float*          h     = (float*)alloc((size_t)MR * DIM * 4);
  float*          y     = (float*)alloc((size_t)MR * DIM * 4);
  unsigned short* yb    = (unsigned short*)alloc((size_t)MR * DIM * 2);
  unsigned short* Winb  = (unsigned short*)alloc((size_t)DIM * VOCAB * 2);
  unsigned short* W1b   = (unsigned short*)alloc((size_t)DEPTH * DFF * DIM * 2);
  unsigned short* W2b   = (unsigned short*)alloc((size_t)DEPTH * DIM * DFF * 2);
  unsigned short* Woutb = (unsigned short*)alloc((size_t)VOCAB * DIM * 2);
  float*          stA   = (float*)alloc((size_t)NB * NC * DIM * 2 * 4);
  float*          carry = (float*)alloc((size_t)NB * NC * DIM * 2 * 4);

  // d_out (134MB f32) doubles as scratch:
  //   act1 (bf16, 33.5MB) at offset 0; split-K partials (4x16MB f32) at 40MB.
  // Final GEMM overwrites d_out fully.
  unsigned short* act1  = (unsigned short*)d_out;
  float*          parts = (float*)((char*)d_out + ((size_t)40 << 20));

  dim3 blk(256);
  cvt_f32_bf16<<<dim3((DIM * VOCAB) / 2048), blk, 0, stream>>>(Win, Winb, DIM * VOCAB / 8);
  cvt_f32_bf16<<<dim3((DEPTH * DFF * DIM) / 2048), blk, 0, stream>>>(W1, W1b, DEPTH * DFF * DIM / 8);
  cvt_f32_bf16<<<dim3((DEPTH * DFF * DIM) / 2048), blk, 0, stream>>>(W2, W2b, DEPTH * DIM * DFF / 8);
  cvt_f32_bf16<<<dim3((VOCAB * DIM) / 2048), blk, 0, stream>>>(Wout, Woutb, VOCAB * DIM / 8);

  // h = x @ Win^T + bin : split-K=4 (Keff=1024), fused f32->bf16 on A=x
  gemm_bt<3, 1><<<dim3(DIM / 128, MR / 128, 4), blk, 0, stream>>>(
      x, Winb, nullptr, parts, nullptr, DIM, VOCAB / 4, VOCAB, VOCAB);
  reduce_sk<0><<<dim3(MR * DIM / 1024), blk, 0, stream>>>(parts, bin, h);

  for (int l = 0; l < DEPTH; ++l) {
    ln_kernel<0><<<dim3(MR / 4), blk, 0, stream>>>(h, ln1w + l * DIM, ln1b + l * DIM, y, nullptr);
    scan_a<<<dim3(NC, NB, DIM / 256), blk, 0, stream>>>(y, phzr + l * DIM, phzi + l * DIM, stA);
    scan_b<<<dim3((NB * DIM) / 256), blk, 0, stream>>>(stA, carry, phzr + l * DIM, phzi + l * DIM,
                                                       lcr + l * DIM, lci + l * DIM);
    scan_c<<<dim3(NC, NB, DIM / 256), blk, 0, stream>>>(y, h, carry, phzr + l * DIM, phzi + l * DIM,
                                                        scl + l * DIM);
    ln_kernel<1><<<dim3(MR / 4), blk, 0, stream>>>(h, ln2w + l * DIM, ln2b + l * DIM, nullptr, yb);
    // act1 = silu(yb @ W1^T + b1), bf16
    gemm_bt<1, 0><<<dim3(DFF / 128, MR / 128, 1), blk, 0, stream>>>(
        yb, W1b + (size_t)l * DFF * DIM, b1 + l * DFF, nullptr, act1, DFF, DIM, DIM, DIM);
    // h += act1 @ W2^T + b2 : split-K=4 (Keff=512)
    gemm_bt<3, 0><<<dim3(DIM / 128, MR / 128, 4), blk, 0, stream>>>(
        act1, W2b + (size_t)l * DIM * DFF, nullptr, parts, nullptr, DIM, DFF / 4, DFF, DFF);
    reduce_sk<1><<<dim3(MR * DIM / 1024), blk, 0, stream>>>(parts, b2 + l * DIM, h);
  }
  ln_kernel<1><<<dim3(MR / 4), blk, 0, stream>>>(h, lnlw, lnlb, nullptr, yb);
  gemm_bt<0, 0><<<dim3(VOCAB / 128, MR / 128, 1), blk, 0, stream>>>(
      yb, Woutb, bout, (float*)d_out, nullptr, VOCAB, DIM, DIM, DIM);
}

// Round 5
// 646.782 us; speedup vs baseline: 1.0336x; 1.0336x over previous
//
#include <hip/hip_runtime.h>
#include <hip/hip_bf16.h>
#include <cstdint>
#include <cstddef>

#define DEPTH 4
#define DIM 512
#define DFF 2048
#define VOCAB 4096
#define NB 2
#define LSEQ 4096
#define MR (NB*LSEQ)      // 8192 rows
#define EPSL 1e-5f
#define NC 128            // scan chunks per sequence
#define TCH 32            // chunk length (NC*TCH == LSEQ)

typedef __attribute__((ext_vector_type(8))) short  s8v;
typedef __attribute__((ext_vector_type(4))) float  f4v;
typedef __attribute__((ext_vector_type(8))) __bf16 bf8v;

__device__ __forceinline__ unsigned short f2b(float f) {
  union { float f; unsigned int u; } v; v.f = f;
  unsigned int r = v.u + 0x7FFFu + ((v.u >> 16) & 1u);   // RNE
  return (unsigned short)(r >> 16);
}

// global->LDS direct load, 16B per lane (LDS dest: wave-uniform base + lane*16).
__device__ __forceinline__ void gld16(const void* g, void* l) {
  __builtin_amdgcn_global_load_lds(
      (const __attribute__((address_space(1))) unsigned int*)(uintptr_t)g,
      (__attribute__((address_space(3))) unsigned int*)(uintptr_t)l,
      16, 0, 0);
}

// counted vmem wait (T4: never drain to 0 in steady state)
template<int N> __device__ __forceinline__ void wvm() {
  if constexpr (N == 8)      asm volatile("s_waitcnt vmcnt(8)" ::: "memory");
  else if constexpr (N == 4) asm volatile("s_waitcnt vmcnt(4)" ::: "memory");
  else                       asm volatile("s_waitcnt vmcnt(0)" ::: "memory");
}

// ---------------- f32 -> bf16 convert (8 elems/thread) ----------------
__global__ void __launch_bounds__(256) cvt_f32_bf16(
    const float* __restrict__ in, unsigned short* __restrict__ out, int n8)
{
  int i = blockIdx.x * 256 + threadIdx.x;
  if (i >= n8) return;
  const f4v* p = (const f4v*)(in + (size_t)i * 8);
  f4v a = p[0], b = p[1];
  s8v o;
  o[0]=(short)f2b(a[0]); o[1]=(short)f2b(a[1]); o[2]=(short)f2b(a[2]); o[3]=(short)f2b(a[3]);
  o[4]=(short)f2b(b[0]); o[5]=(short)f2b(b[1]); o[6]=(short)f2b(b[2]); o[7]=(short)f2b(b[3]);
  *(s8v*)(out + (size_t)i * 8) = o;
}

// ---------------- LayerNorm (1 wave / 512-row) ----------------
// MODE 0: out = silu(LN(x)) as f32 ; MODE 1: out = LN(x) as bf16
template<int MODE>
__global__ void __launch_bounds__(256) ln_kernel(
    const float* __restrict__ x, const float* __restrict__ w, const float* __restrict__ b,
    float* __restrict__ outf, unsigned short* __restrict__ outb)
{
  int row  = blockIdx.x * 4 + (threadIdx.x >> 6);
  int lane = threadIdx.x & 63;
  const float* xp = x + (size_t)row * DIM + lane * 8;
  f4v v0 = *(const f4v*)xp;
  f4v v1 = *(const f4v*)(xp + 4);
  float s = 0.f, s2 = 0.f;
#pragma unroll
  for (int j = 0; j < 4; ++j) { s += v0[j]; s2 += v0[j]*v0[j]; s += v1[j]; s2 += v1[j]*v1[j]; }
#pragma unroll
  for (int off = 32; off; off >>= 1) { s += __shfl_xor(s, off, 64); s2 += __shfl_xor(s2, off, 64); }
  float mu = s * (1.f / DIM);
  float rs = rsqrtf(s2 * (1.f / DIM) - mu * mu + EPSL);
  int c = lane * 8;
  f4v w0 = *(const f4v*)(w + c), w1 = *(const f4v*)(w + c + 4);
  f4v b0 = *(const f4v*)(b + c), b1 = *(const f4v*)(b + c + 4);
  float ov[8];
#pragma unroll
  for (int j = 0; j < 8; ++j) {
    float xv = (j < 4) ? v0[j] : v1[j - 4];
    float wv = (j < 4) ? w0[j] : w1[j - 4];
    float bv = (j < 4) ? b0[j] : b1[j - 4];
    float o = (xv - mu) * rs * wv + bv;
    if (MODE == 0) o = o / (1.f + __expf(-o));   // silu
    ov[j] = o;
  }
  if (MODE == 0) {
    f4v o0 = {ov[0], ov[1], ov[2], ov[3]};
    f4v o1 = {ov[4], ov[5], ov[6], ov[7]};
    *(f4v*)(outf + (size_t)row * DIM + c)     = o0;
    *(f4v*)(outf + (size_t)row * DIM + c + 4) = o1;
  } else {
    s8v o;
#pragma unroll
    for (int j = 0; j < 8; ++j) o[j] = (short)f2b(ov[j]);
    *(s8v*)(outb + (size_t)row * DIM + c) = o;
  }
}

// ---------------- sconv scan ----------------
__device__ __forceinline__ void phz2p(float re, float im, float& pre, float& pim) {
  float r = sqrtf(re * re + im * im);
  float t = (r > 1e-20f) ? (tanhf(r) / r) : 1.0f;
  pre = t * re; pim = t * im;
}

// Phase A: per-chunk local scan from 0; store chunk-end state [NB][NC][DIM][2]
__global__ void __launch_bounds__(256) scan_a(
    const float* __restrict__ y, const float* __restrict__ pr, const float* __restrict__ pi,
    float* __restrict__ stA)
{
  int d = blockIdx.z * 256 + threadIdx.x;
  int b = blockIdx.y, c = blockIdx.x;
  float pre, pim; phz2p(pr[d], pi[d], pre, pim);
  const float* yp = y + ((size_t)b * LSEQ + (size_t)c * TCH) * DIM + d;
  float sre = 0.f, sim = 0.f;
#pragma unroll 8
  for (int j = 0; j < TCH; ++j) {
    float xv = yp[(size_t)j * DIM];
    float nre = fmaf(pre, sre, fmaf(-pim, sim, xv));
    float nim = fmaf(pre, sim, pim * sre);
    sre = nre; sim = nim;
  }
  size_t o = (((size_t)b * NC + c) * DIM + d) * 2;
  stA[o] = sre; stA[o + 1] = sim;
}

// Phase B: sequential carry over chunks; carry[b][c] = state entering chunk c
__global__ void __launch_bounds__(256) scan_b(
    const float* __restrict__ stA, float* __restrict__ carry,
    const float* __restrict__ pr, const float* __restrict__ pi,
    const float* __restrict__ lcr, const float* __restrict__ lci)
{
  int idx = blockIdx.x * 256 + threadIdx.x;   // 0..NB*DIM-1
  int b = idx >> 9, d = idx & (DIM - 1);
  float pre, pim; phz2p(pr[d], pi[d], pre, pim);
  float qre = pre, qim = pim;                  // p^TCH, TCH=32 -> 5 squarings
#pragma unroll
  for (int t = 0; t < 5; ++t) { float nr = qre*qre - qim*qim; float ni = 2.f*qre*qim; qre = nr; qim = ni; }
  float cre = lcr[d], cim = lci[d];
#pragma unroll 4
  for (int c = 0; c < NC; ++c) {
    size_t o = (((size_t)b * NC + c) * DIM + d) * 2;
    carry[o] = cre; carry[o + 1] = cim;
    float are = stA[o], aim = stA[o + 1];
    float nr = fmaf(qre, cre, fmaf(-qim, cim, are));
    float ni = fmaf(qre, cim, fmaf(qim, cre, aim));
    cre = nr; cim = ni;
  }
}

// Phase C: replay chunk with true carry; fused h += Re(s)*scl
__global__ void __launch_bounds__(256) scan_c(
    const float* __restrict__ y, float* __restrict__ h, const float* __restrict__ carry,
    const float* __restrict__ pr, const float* __restrict__ pi,
    const float* __restrict__ scl)
{
  int d = blockIdx.z * 256 + threadIdx.x;
  int b = blockIdx.y, c = blockIdx.x;
  float pre, pim; phz2p(pr[d], pi[d], pre, pim);
  size_t o = (((size_t)b * NC + c) * DIM + d) * 2;
  float sre = carry[o], sim = carry[o + 1];
  float sc = scl[d];
  const float* yp = y + ((size_t)b * LSEQ + (size_t)c * TCH) * DIM + d;
  float*       hp = h + ((size_t)b * LSEQ + (size_t)c * TCH) * DIM + d;
#pragma unroll 8
  for (int j = 0; j < TCH; ++j) {
    float xv = yp[(size_t)j * DIM];
    float nre = fmaf(pre, sre, fmaf(-pim, sim, xv));
    float nim = fmaf(pre, sim, pim * sre);
    sre = nre; sim = nim;
    hp[(size_t)j * DIM] += sre * sc;
  }
}

// ---------------- pipelined bf16 MFMA GEMM, A[M,K] x B[N,K]^T, 128x128 ----------------
// Depth-2 counted-vmcnt pipeline, 3 LDS buffer pairs (48KB). Per iteration:
//   stage(kt+2) -> wvm<8> (own loads: tile kt retired) -> s_barrier (collective)
//   -> sched_barrier(0) (fence: no ds_read hoists above barrier) -> ds_read+MFMA
//   -> sched_barrier(0) -> s_barrier (no wave re-stages a buffer still being read).
// Split-K via blockIdx.z; lda/ldb are full row strides.
// EPI 0: Cf = acc + bias ; EPI 1: Cb = bf16(silu(acc+bias)) ; EPI 3: raw partial
template<int EPI>
__global__ void __launch_bounds__(256, 3) gemm_p(
    const unsigned short* __restrict__ A, const unsigned short* __restrict__ Bm,
    const float* __restrict__ bias,
    float* __restrict__ Cf, unsigned short* __restrict__ Cb,
    int N, int Keff, int lda, int ldb)
{
  __shared__ unsigned short As[3][128 * 32];
  __shared__ unsigned short Bs[3][128 * 32];
  const int tid  = threadIdx.x;
  const int lane = tid & 63, wave = tid >> 6;
  const int wm = wave >> 1, wn = wave & 1;
  const int fr = lane & 15, fq = lane >> 4;
  const int bz = blockIdx.z;

  // chunked bijective XCD swizzle within each z-slice (nwg_xy % 8 == 0 for all grids)
  int bx, by;
  {
    int gx = gridDim.x;
    int nwg = gx * gridDim.y;
    int b = blockIdx.y * gx + blockIdx.x;
    int lid = (b & 7) * (nwg >> 3) + (b >> 3);
    bx = lid % gx; by = lid / gx;
  }
  const int m0 = by * 128, n0 = bx * 128;
  const int koff = bz * Keff;
  const int nkt = Keff >> 5;          // >= 16 for all our shapes

  f4v acc[4][4];
#pragma unroll
  for (int i = 0; i < 4; ++i)
#pragma unroll
    for (int j = 0; j < 4; ++j) acc[i][j] = (f4v){0.f, 0.f, 0.f, 0.f};

  const int row2 = tid >> 2, col2 = (tid & 3) << 3;   // staging coords (idx = tid / 256+tid)
  auto stage = [&](int buf, int kt) {                  // 4 gld16 / thread (2A + 2B)
    const unsigned short* Ab = A  + (size_t)m0 * lda + koff + kt * 32;
    const unsigned short* Bb = Bm + (size_t)n0 * ldb + koff + kt * 32;
    gld16(Ab + (size_t)row2 * lda + col2,        &As[buf][tid * 8]);
    gld16(Ab + (size_t)(row2 + 64) * lda + col2, &As[buf][(256 + tid) * 8]);
    gld16(Bb + (size_t)row2 * ldb + col2,        &Bs[buf][tid * 8]);
    gld16(Bb + (size_t)(row2 + 64) * ldb + col2, &Bs[buf][(256 + tid) * 8]);
  };

  // prologue: tiles 0,1 into bufs 0,1
  stage(0, 0);
  stage(1, 1);

  int b0 = 0, b1 = 1, b2 = 2;   // compute buf, next buf, stage buf (rotating, uniform)
  for (int kt = 0; kt < nkt; ++kt) {
    bool pf = (kt + 2 < nkt);
    if (pf) stage(b2, kt + 2);
    if (pf)                    wvm<8>();   // tiles kt+1,kt+2 in flight; kt retired
    else if (kt + 1 < nkt)     wvm<4>();   // tile kt+1 in flight
    else                       wvm<0>();
    __builtin_amdgcn_s_barrier();          // collective: everyone's tile-kt loads landed
    __builtin_amdgcn_sched_barrier(0);     // fence: ds_reads must not hoist above barrier
    bf8v av[4], bv[4];
#pragma unroll
    for (int i = 0; i < 4; ++i)
      av[i] = *(const bf8v*)&As[b0][(wm * 64 + i * 16 + fr) * 32 + fq * 8];
#pragma unroll
    for (int j = 0; j < 4; ++j)
      bv[j] = *(const bf8v*)&Bs[b0][(wn * 64 + j * 16 + fr) * 32 + fq * 8];
#pragma unroll
    for (int i = 0; i < 4; ++i)
#pragma unroll
      for (int j = 0; j < 4; ++j)
        acc[i][j] = __builtin_amdgcn_mfma_f32_16x16x32_bf16(av[i], bv[j], acc[i][j], 0, 0, 0);
    __builtin_amdgcn_sched_barrier(0);     // fence: ds_reads must not sink below barrier
    __builtin_amdgcn_s_barrier();          // nobody re-stages b0 while others still read it
    int t = b0; b0 = b1; b1 = b2; b2 = t;
  }

  // epilogue: C[m0 + wm*64 + i*16 + fq*4 + r][n0 + wn*64 + j*16 + fr]
  const size_t pbase = (EPI == 3) ? (size_t)bz * MR * N : 0;
#pragma unroll
  for (int j = 0; j < 4; ++j) {
    const int col = n0 + wn * 64 + j * 16 + fr;
    const float bsv = (EPI == 3) ? 0.f : bias[col];
#pragma unroll
    for (int i = 0; i < 4; ++i) {
#pragma unroll
      for (int r = 0; r < 4; ++r) {
        const int row = m0 + wm * 64 + i * 16 + fq * 4 + r;
        const size_t off = (size_t)row * N + col;
        float v = acc[i][j][r] + bsv;
        if constexpr (EPI == 0) {
          Cf[off] = v;
        } else if constexpr (EPI == 1) {
          float sv = v / (1.f + __expf(-v));
          Cb[off] = f2b(sv);
        } else {
          Cf[pbase + off] = v;
        }
      }
    }
  }
}

// ---------------- split-K reduce: out = (RES? out:0) + sum_4(parts) + bias ----------------
template<int RES>
__global__ void __launch_bounds__(256) reduce_sk(
    const float* __restrict__ parts, const float* __restrict__ bias,
    float* __restrict__ out)
{
  size_t i = ((size_t)blockIdx.x * 256 + threadIdx.x) * 4;
  const size_t st = (size_t)MR * DIM;
  f4v v = *(const f4v*)(parts + i);
  v += *(const f4v*)(parts + st + i);
  v += *(const f4v*)(parts + 2 * st + i);
  v += *(const f4v*)(parts + 3 * st + i);
  int c = (int)(i & (DIM - 1));
  v += *(const f4v*)(bias + c);
  if (RES) v += *(const f4v*)(out + i);
  *(f4v*)(out + i) = v;
}

// ---------------- orchestration ----------------
extern "C" void kernel_launch(void* const* d_in, const int* in_sizes, int n_in,
                              void* d_out, int out_size, void* d_ws, size_t ws_size,
                              hipStream_t stream)
{
  (void)in_sizes; (void)n_in; (void)out_size; (void)ws_size;
  const float* x    = (const float*)d_in[0];
  const float* Win  = (const float*)d_in[1];
  const float* bin  = (const float*)d_in[2];
  const float* ln1w = (const float*)d_in[3];
  const float* ln1b = (const float*)d_in[4];
  const float* phzr = (const float*)d_in[5];
  const float* phzi = (const float*)d_in[6];
  const float* lcr  = (const float*)d_in[7];
  const float* lci  = (const float*)d_in[8];
  const float* scl  = (const float*)d_in[9];
  const float* ln2w = (const float*)d_in[10];
  const float* ln2b = (const float*)d_in[11];
  const float* W1   = (const float*)d_in[12];
  const float* b1   = (const float*)d_in[13];
  const float* W2   = (const float*)d_in[14];
  const float* b2   = (const float*)d_in[15];
  const float* lnlw = (const float*)d_in[16];
  const float* lnlb = (const float*)d_in[17];
  const float* Wout = (const float*)d_in[18];
  const float* bout = (const float*)d_in[19];

  char* wsp = (char*)d_ws;
  auto alloc = [&](size_t bytes) { char* p = wsp; wsp += (bytes + 255) & ~(size_t)255; return p; };
  float*          h     = (float*)alloc((size_t)MR * DIM * 4);
  float*          y     = (float*)alloc((size_t)MR * DIM * 4);
  unsigned short* yb    = (unsigned short*)alloc((size_t)MR * DIM * 2);
  unsigned short* Winb  = (unsigned short*)alloc((size_t)DIM * VOCAB * 2);
  unsigned short* W1b   = (unsigned short*)alloc((size_t)DEPTH * DFF * DIM * 2);
  unsigned short* W2b   = (unsigned short*)alloc((size_t)DEPTH * DIM * DFF * 2);
  unsigned short* Woutb = (unsigned short*)alloc((size_t)VOCAB * DIM * 2);
  float*          stA   = (float*)alloc((size_t)NB * NC * DIM * 2 * 4);
  float*          carry = (float*)alloc((size_t)NB * NC * DIM * 2 * 4);

  // d_out (128 MiB) doubles as scratch:
  //   xb   (bf16, 64 MiB) at [0, 64Mi)   — dies after token_in GEMM
  //   act1 (bf16, 32 MiB) at [0, 32Mi)   — per-layer FFN activation
  //   parts (4 x 16 MiB f32) at [64Mi, 128Mi) — split-K partials (no alias with xb/act1)
  // Final GEMM overwrites d_out fully.
  unsigned short* xb    = (unsigned short*)d_out;
  unsigned short* act1  = (unsigned short*)d_out;
  float*          parts = (float*)((char*)d_out + ((size_t)64 << 20));

  dim3 blk(256);
  cvt_f32_bf16<<<dim3(((size_t)MR * VOCAB) / 2048), blk, 0, stream>>>(x, xb, (int)(((size_t)MR * VOCAB) / 8));
  cvt_f32_bf16<<<dim3((DIM * VOCAB) / 2048), blk, 0, stream>>>(Win, Winb, DIM * VOCAB / 8);
  cvt_f32_bf16<<<dim3((DEPTH * DFF * DIM) / 2048), blk, 0, stream>>>(W1, W1b, DEPTH * DFF * DIM / 8);
  cvt_f32_bf16<<<dim3((DEPTH * DFF * DIM) / 2048), blk, 0, stream>>>(W2, W2b, DEPTH * DIM * DFF / 8);
  cvt_f32_bf16<<<dim3((VOCAB * DIM) / 2048), blk, 0, stream>>>(Wout, Woutb, VOCAB * DIM / 8);

  // h = x @ Win^T + bin : split-K=4 (Keff=1024)
  gemm_p<3><<<dim3(DIM / 128, MR / 128, 4), blk, 0, stream>>>(
      xb, Winb, nullptr, parts, nullptr, DIM, VOCAB / 4, VOCAB, VOCAB);
  reduce_sk<0><<<dim3(MR * DIM / 1024), blk, 0, stream>>>(parts, bin, h);

  for (int l = 0; l < DEPTH; ++l) {
    ln_kernel<0><<<dim3(MR / 4), blk, 0, stream>>>(h, ln1w + l * DIM, ln1b + l * DIM, y, nullptr);
    scan_a<<<dim3(NC, NB, DIM / 256), blk, 0, stream>>>(y, phzr + l * DIM, phzi + l * DIM, stA);
    scan_b<<<dim3((NB * DIM) / 256), blk, 0, stream>>>(stA, carry, phzr + l * DIM, phzi + l * DIM,
                                                       lcr + l * DIM, lci + l * DIM);
    scan_c<<<dim3(NC, NB, DIM / 256), blk, 0, stream>>>(y, h, carry, phzr + l * DIM, phzi + l * DIM,
                                                        scl + l * DIM);
    ln_kernel<1><<<dim3(MR / 4), blk, 0, stream>>>(h, ln2w + l * DIM, ln2b + l * DIM, nullptr, yb);
    // act1 = silu(yb @ W1^T + b1), bf16
    gemm_p<1><<<dim3(DFF / 128, MR / 128, 1), blk, 0, stream>>>(
        yb, W1b + (size_t)l * DFF * DIM, b1 + l * DFF, nullptr, act1, DFF, DIM, DIM, DIM);
    // h += act1 @ W2^T + b2 : split-K=4 (Keff=512)
    gemm_p<3><<<dim3(DIM / 128, MR / 128, 4), blk, 0, stream>>>(
        act1, W2b + (size_t)l * DIM * DFF, nullptr, parts, nullptr, DIM, DFF / 4, DFF, DFF);
    reduce_sk<1><<<dim3(MR * DIM / 1024), blk, 0, stream>>>(parts, b2 + l * DIM, h);
  }
  ln_kernel<1><<<dim3(MR / 4), blk, 0, stream>>>(h, lnlw, lnlb, nullptr, yb);
  gemm_p<0><<<dim3(VOCAB / 128, MR / 128, 1), blk, 0, stream>>>(
      yb, Woutb, bout, (float*)d_out, nullptr, VOCAB, DIM, DIM, DIM);
}